// Round 13
// baseline (646.306 us; speedup 1.0000x reference)
//
#include <hip/hip_runtime.h>
#include <hip/hip_bf16.h>

// GraphMatchingLayer, round 13: kill the LDS-broadcast floor.
// r12 diagnosis: edge kernel is LDS-return-bandwidth-bound (8KB/edge broadcast
// = 64 cyc/edge/CU = ~167us floor; invariant across r7-r12). Fix: broadcast ea
// through the SGPR operand path (free at issue). To make the scalar loads
// sequential (r5/r6 showed random s_loads serialize), k_scatter2 stores ea
// rows in CSR order (eas[p] = ea[e], 128B-aligned full-line writes).
// k_edge10: zero LDS, sequential s_load_dwordx16 stream + SGPR-operand FMAs.
// Fallback to the r12 path when ws_size can't hold eas (~264MB total).

#define TPB 256
#define EDGE_BLOCKS 2048
#define SCAT_BLOCKS 2048
#define PREP_BLOCKS 1024
#define NODE_BLOCKS 1024

typedef float v2f __attribute__((ext_vector_type(2)));
typedef float v4f __attribute__((ext_vector_type(4)));

// 32-wide dense segment (weights via wave-uniform address -> scalar loads)
#define SEG32(SRC, NCH, KB, W, COL, ACC)                                \
  for (int kc_ = 0; kc_ < (NCH); ++kc_) {                               \
    const float4 a_ = ((const float4*)(SRC))[kc_];                      \
    const float av_[4] = {a_.x, a_.y, a_.z, a_.w};                      \
    _Pragma("unroll")                                                   \
    for (int j_ = 0; j_ < 4; ++j_) {                                    \
      const float ak_ = av_[j_];                                        \
      const float* wr_ = (W) + ((KB) + kc_ * 4 + j_) * 64 + (COL);      \
      _Pragma("unroll")                                                 \
      for (int cc_ = 0; cc_ < 32; ++cc_)                                \
        ACC[cc_] = fmaf(ak_, wr_[cc_], ACC[cc_]);                       \
    }                                                                   \
  }

// ---------------- CSR build ----------------

__global__ __launch_bounds__(TPB)
void k_hist(const int* __restrict__ ei, int* __restrict__ deg, int E) {
  const int stride = gridDim.x * TPB;
  for (int e = blockIdx.x * TPB + threadIdx.x; e < E; e += stride)
    atomicAdd(&deg[ei[e]], 1);
}

__global__ __launch_bounds__(TPB)
void k_red(const int* __restrict__ deg, int* __restrict__ bsum, int N) {
  __shared__ int s[TPB];
  const int tid = threadIdx.x;
  const int g = (blockIdx.x * TPB + tid) * 4;
  int v = 0;
  #pragma unroll
  for (int j = 0; j < 4; ++j) if (g + j < N) v += deg[g + j];
  s[tid] = v;
  __syncthreads();
  for (int off = TPB / 2; off > 0; off >>= 1) {
    if (tid < off) s[tid] += s[tid + off];
    __syncthreads();
  }
  if (tid == 0) bsum[blockIdx.x] = s[0];
}

__global__ __launch_bounds__(TPB)
void k_apply2(const int* __restrict__ deg, const int* __restrict__ bsum,
              int* __restrict__ cur, int N) {
  __shared__ int s[TPB];
  __shared__ int sbase;
  const int tid = threadIdx.x;
  const int g = (blockIdx.x * TPB + tid) * 4;

  if (tid < 64) {
    int v = 0;
    for (int i = tid; i < (int)blockIdx.x; i += 64) v += bsum[i];
    #pragma unroll
    for (int off = 32; off > 0; off >>= 1) v += __shfl_down(v, off);
    if (tid == 0) sbase = v;
  }

  int d[4];
  int v = 0;
  #pragma unroll
  for (int j = 0; j < 4; ++j) { d[j] = (g + j < N) ? deg[g + j] : 0; v += d[j]; }
  s[tid] = v;
  __syncthreads();
  for (int off = 1; off < TPB; off <<= 1) {
    int t = (tid >= off) ? s[tid - off] : 0;
    __syncthreads();
    s[tid] += t;
    __syncthreads();
  }
  int base = sbase + s[tid] - v;
  #pragma unroll
  for (int j = 0; j < 4; ++j)
    if (g + j < N) { cur[g + j] = base; base += d[j]; }
}

// new-path scatter: col[p] = c and eas[p] = ea[e] (CSR-ordered ea copy)
__global__ __launch_bounds__(TPB)
void k_scatter2(const int* __restrict__ ei, int* __restrict__ cur,
                int* __restrict__ col, float* __restrict__ eas,
                const float* __restrict__ ea, int E) {
  const int stride = gridDim.x * TPB;
  for (int e = blockIdx.x * TPB + threadIdx.x; e < E; e += stride) {
    const int r = ei[e];
    const int c = ei[E + e];
    int p = atomicAdd(&cur[r], 1);
    col[p] = c;
    const float4* src = (const float4*)(ea + (size_t)e * 32);
    float4* dst = (float4*)(eas + (size_t)p * 32);
    #pragma unroll
    for (int j = 0; j < 8; ++j) dst[j] = src[j];
  }
}

// fallback scatter (r12): ec int2
__global__ __launch_bounds__(TPB)
void k_scatter(const int* __restrict__ ei, int* __restrict__ cur,
               int2* __restrict__ ec, int E) {
  const int stride = gridDim.x * TPB;
  for (int e = blockIdx.x * TPB + threadIdx.x; e < E; e += stride) {
    const int r = ei[e];
    const int c = ei[E + e];
    int p = atomicAdd(&cur[r], 1);
    ec[p] = make_int2(e, c);
  }
}

// ---------------- U/V precompute (grid-stride wave units) ----------------

__global__ __launch_bounds__(TPB)
void k_prep4(const float* __restrict__ x,
             const float* __restrict__ ew1, const float* __restrict__ eb1,
             float* __restrict__ U, float* __restrict__ V, int N)
{
  const int lane = threadIdx.x & 63;
  const int wid  = __builtin_amdgcn_readfirstlane(threadIdx.x >> 6);
  const int nunits = 4 * ((N + 63) / 64);
  const int wstride = gridDim.x * 4;

  for (int unit = blockIdx.x * 4 + wid; unit < nunits; unit += wstride) {
    const int q = unit & 3;
    const int n = (unit >> 2) * 64 + lane;
    if (n >= N) continue;

    const int uv = q >> 1;
    const int h = (q & 1) * 32;
    const float* W = ew1 + uv * 64 * 64;

    float acc[32];
    if (uv) {
      #pragma unroll
      for (int j = 0; j < 32; ++j) acc[j] = 0.f;
    } else {
      #pragma unroll
      for (int j = 0; j < 32; ++j) acc[j] = eb1[h + j];
    }
    SEG32(x + (size_t)n * 64, 16, 0, W, h, acc)

    float* dst = (uv ? V : U) + (size_t)n * 64 + h;
    float4* d4 = (float4*)dst;
    #pragma unroll
    for (int c4 = 0; c4 < 8; ++c4)
      d4[c4] = make_float4(acc[c4*4+0], acc[c4*4+1], acc[c4*4+2], acc[c4*4+3]);
  }
}

// ---------------- edge phase, new path: SGPR-broadcast ea, zero LDS ----------------

#define EDGE_FMA32(EP, VV, ACC)                                         \
  {                                                                     \
    float t0_ = u + (VV), t1_ = 0.f, t2_ = 0.f, t3_ = 0.f;              \
    _Pragma("unroll")                                                   \
    for (int k_ = 0; k_ < 32; k_ += 4) {                                \
      t0_ = fmaf((EP)[k_ + 0], w[k_ + 0], t0_);                         \
      t1_ = fmaf((EP)[k_ + 1], w[k_ + 1], t1_);                         \
      t2_ = fmaf((EP)[k_ + 2], w[k_ + 2], t2_);                         \
      t3_ = fmaf((EP)[k_ + 3], w[k_ + 3], t3_);                         \
    }                                                                   \
    ACC += fmaxf((t0_ + t1_) + (t2_ + t3_), 0.f);                       \
  }

__global__ __launch_bounds__(TPB, 6)
void k_edge10(const float* __restrict__ U, const float* __restrict__ V,
              const float* __restrict__ eas, const int* __restrict__ col,
              const float* __restrict__ ew1,
              const int* __restrict__ deg, const int* __restrict__ cur,
              float* __restrict__ H, int N)
{
  const int lane = threadIdx.x & 63;
  const int wid  = __builtin_amdgcn_readfirstlane(threadIdx.x >> 6);

  // this lane's W1c column (pinned: cannot be rematerialized)
  const float* wcol = ew1 + 128 * 64 + lane;
  float w[32];
  #pragma unroll
  for (int k = 0; k < 32; ++k) w[k] = wcol[k * 64];
  #pragma unroll
  for (int k = 0; k < 32; k += 4)
    asm volatile("" : "+v"(w[k]), "+v"(w[k+1]), "+v"(w[k+2]), "+v"(w[k+3]));

  const int wstride = gridDim.x * 4;

  for (int n = blockIdx.x * 4 + wid; n < N; n += wstride) {
    const int d  = __builtin_amdgcn_readfirstlane(deg[n]);
    const int s0 = __builtin_amdgcn_readfirstlane(cur[n]) - d;

    const float u = U[(size_t)n * 64 + lane];
    const float* ep = eas + (size_t)s0 * 32;   // wave-uniform, sequential
    const int*  cp = col + s0;                 // wave-uniform, sequential
    float acc = 0.f;

    int i = 0;
    for (; i + 2 <= d; i += 2) {
      const int c0 = __builtin_amdgcn_readfirstlane(cp[i]);
      const int c1 = __builtin_amdgcn_readfirstlane(cp[i + 1]);
      const float v0 = V[(size_t)c0 * 64 + lane];   // coalesced row
      const float v1 = V[(size_t)c1 * 64 + lane];
      const float* e0 = ep + (size_t)i * 32;        // -> s_load_dwordx16 x2
      const float* e1 = e0 + 32;
      EDGE_FMA32(e0, v0, acc)
      EDGE_FMA32(e1, v1, acc)
    }
    if (i < d) {
      const int c0 = __builtin_amdgcn_readfirstlane(cp[i]);
      const float v0 = V[(size_t)c0 * 64 + lane];
      const float* e0 = ep + (size_t)i * 32;
      EDGE_FMA32(e0, v0, acc)
    }

    H[(size_t)n * 64 + lane] = acc;
  }
}

// ---------------- edge phase, fallback (r12 verbatim) ----------------

__global__ __launch_bounds__(TPB, 4)
void k_edge9(const float* __restrict__ U, const float* __restrict__ V,
             const float* __restrict__ ea,
             const float* __restrict__ ew1,
             const int* __restrict__ deg, const int* __restrict__ cur,
             const int2* __restrict__ ec,
             float* __restrict__ H, int N)
{
  __shared__ float sbuf[4 * 256];

  const int lane = threadIdx.x & 63;
  const int wid  = __builtin_amdgcn_readfirstlane(threadIdx.x >> 6);

  float* lw = sbuf + wid * 256;
  const int g = lane >> 3;
  const int o = lane & 7;

  const float* wcol = ew1 + 128 * 64 + lane;
  v2f w2[16];
  #pragma unroll
  for (int i = 0; i < 16; ++i) {
    w2[i].x = wcol[(2 * i) * 64];
    w2[i].y = wcol[(2 * i + 1) * 64];
  }
  asm volatile("" : "+v"(w2[0]), "+v"(w2[1]), "+v"(w2[2]), "+v"(w2[3]),
                    "+v"(w2[4]), "+v"(w2[5]), "+v"(w2[6]), "+v"(w2[7]),
                    "+v"(w2[8]), "+v"(w2[9]), "+v"(w2[10]), "+v"(w2[11]),
                    "+v"(w2[12]), "+v"(w2[13]), "+v"(w2[14]), "+v"(w2[15]));

  const int wstride = gridDim.x * 4;

  for (int n = blockIdx.x * 4 + wid; n < N; n += wstride) {
    const int d  = __builtin_amdgcn_readfirstlane(deg[n]);
    const int s0 = __builtin_amdgcn_readfirstlane(cur[n]) - d;

    const float u = U[(size_t)n * 64 + lane];
    const int2* ecp = ec + s0;
    float acc = 0.f;

    for (int i = 0; i < d; i += 8) {
      const int rem = d - i;
      const int gg = (g < rem) ? g : rem - 1;

      const int2 ecv = ecp[i + gg];
      const float4 eav = *(const float4*)(ea + (size_t)ecv.x * 32 + o * 4);

      const int c0 = __builtin_amdgcn_readlane(ecv.y, 0);
      const int c1 = __builtin_amdgcn_readlane(ecv.y, 8);
      const int c2 = __builtin_amdgcn_readlane(ecv.y, 16);
      const int c3 = __builtin_amdgcn_readlane(ecv.y, 24);
      const int c4 = __builtin_amdgcn_readlane(ecv.y, 32);
      const int c5 = __builtin_amdgcn_readlane(ecv.y, 40);
      const int c6 = __builtin_amdgcn_readlane(ecv.y, 48);
      const int c7 = __builtin_amdgcn_readlane(ecv.y, 56);
      const float v0 = V[(size_t)c0 * 64 + lane];
      const float v1 = V[(size_t)c1 * 64 + lane];
      const float v2 = V[(size_t)c2 * 64 + lane];
      const float v3 = V[(size_t)c3 * 64 + lane];
      const float v4 = V[(size_t)c4 * 64 + lane];
      const float v5 = V[(size_t)c5 * 64 + lane];
      const float v6 = V[(size_t)c6 * 64 + lane];
      const float v7 = V[(size_t)c7 * 64 + lane];

      *(float4*)(lw + lane * 4) = eav;

      const float vs[8] = {v0, v1, v2, v3, v4, v5, v6, v7};
      #pragma unroll
      for (int j = 0; j < 8; ++j) {
        const float* er = lw + j * 32;
        v2f t0 = {u, 0.f}, t1 = {0.f, 0.f}, t2 = {0.f, 0.f}, t3 = {0.f, 0.f};
        #pragma unroll
        for (int kq = 0; kq < 8; kq += 2) {
          const v4f qa = *(const v4f*)(er + kq * 4);
          const v4f qb = *(const v4f*)(er + kq * 4 + 4);
          t0 = __builtin_elementwise_fma(qa.lo, w2[2 * kq],     t0);
          t1 = __builtin_elementwise_fma(qa.hi, w2[2 * kq + 1], t1);
          t2 = __builtin_elementwise_fma(qb.lo, w2[2 * kq + 2], t2);
          t3 = __builtin_elementwise_fma(qb.hi, w2[2 * kq + 3], t3);
        }
        const v2f s2 = (t0 + t1) + (t2 + t3);
        const float s = fmaxf(s2.x + s2.y + vs[j], 0.f);
        acc += (j < rem) ? s : 0.f;
      }
    }

    H[(size_t)n * 64 + lane] = acc;
  }
}

// ---------------- node MLP (grid-stride) ----------------

__global__ __launch_bounds__(TPB)
void k_node4(const float* __restrict__ x, const float* __restrict__ Hin,
             const int* __restrict__ deg,
             const float* __restrict__ ew2, const float* __restrict__ eb2,
             const float* __restrict__ nw1, const float* __restrict__ nb1,
             const float* __restrict__ nw2, const float* __restrict__ nb2,
             float* __restrict__ out, int N)
{
  __shared__ float sb[2][64 * 65];

  const int tid  = threadIdx.x;
  const int wv   = __builtin_amdgcn_readfirstlane(tid >> 6);
  const int lane = tid & 63;
  const int grp  = wv >> 1;
  const int h    = (wv & 1) * 32;

  for (int base = blockIdx.x * 128; base < N; base += gridDim.x * 128) {
    const int n  = base + grp * 64 + lane;
    const bool valid = (n < N);
    const int nn = valid ? n : (N - 1);

    float* srow = &sb[grp][lane * 65];

    float acc[32];
    const float dg = (float)deg[nn];
    #pragma unroll
    for (int j = 0; j < 32; ++j) acc[j] = dg * eb2[h + j];
    SEG32(Hin + (size_t)nn * 64, 16, 0, ew2, h, acc)

    #pragma unroll
    for (int j = 0; j < 32; ++j) srow[h + j] = acc[j];
    __syncthreads();

    float bcc[32];
    #pragma unroll
    for (int j = 0; j < 32; ++j) bcc[j] = nb1[h + j];
    SEG32(x + (size_t)nn * 64, 16, 0, nw1, h, bcc)
    for (int k = 0; k < 64; ++k) {
      const float ak = srow[k];
      const float* wr = nw1 + (64 + k) * 64 + h;
      #pragma unroll
      for (int cc = 0; cc < 32; ++cc) bcc[cc] = fmaf(ak, wr[cc], bcc[cc]);
    }
    __syncthreads();

    #pragma unroll
    for (int j = 0; j < 32; ++j) srow[h + j] = fmaxf(bcc[j], 0.f);
    __syncthreads();

    float occ[32];
    #pragma unroll
    for (int j = 0; j < 32; ++j) occ[j] = nb2[h + j];
    for (int k = 0; k < 64; ++k) {
      const float ak = srow[k];
      const float* wr = nw2 + k * 64 + h;
      #pragma unroll
      for (int cc = 0; cc < 32; ++cc) occ[cc] = fmaf(ak, wr[cc], occ[cc]);
    }

    if (valid) {
      float4* ov = (float4*)(out + (size_t)n * 64 + h);
      #pragma unroll
      for (int c4 = 0; c4 < 8; ++c4)
        ov[c4] = make_float4(occ[c4*4+0], occ[c4*4+1], occ[c4*4+2], occ[c4*4+3]);
    }
    __syncthreads();
  }
}

// ---------------- launch ----------------

extern "C" void kernel_launch(void* const* d_in, const int* in_sizes, int n_in,
                              void* d_out, int out_size, void* d_ws, size_t ws_size,
                              hipStream_t stream) {
  const float* x   = (const float*)d_in[0];
  const int*   ei  = (const int*)d_in[1];
  const float* ea  = (const float*)d_in[2];
  const float* ew1 = (const float*)d_in[3];
  const float* eb1 = (const float*)d_in[4];
  const float* ew2 = (const float*)d_in[5];
  const float* eb2 = (const float*)d_in[6];
  const float* nw1 = (const float*)d_in[7];
  const float* nb1 = (const float*)d_in[8];
  const float* nw2 = (const float*)d_in[9];
  const float* nb2 = (const float*)d_in[10];
  float* out = (float*)d_out;

  const int N = in_sizes[0] / 64;   // 100000
  const int E = in_sizes[1] / 2;    // 1600000

  const int NT = (N + 3) / 4;
  const int NB = (NT + TPB - 1) / TPB;

  // new-path layout: eas first (128B-aligned rows)
  const size_t eas_f   = (size_t)E * 32;                   // 204.8 MB
  const size_t uv_f    = 2 * (size_t)N * 64;               // 51.2 MB
  const size_t ints    = (size_t)2 * N + 1024 + E;         // deg,cur,bsum,col
  const size_t need_new = (eas_f + uv_f) * 4 + ints * 4;

  if (ws_size >= need_new) {
    float* eas = (float*)d_ws;                  // E*32
    float* U   = eas + eas_f;                   // N*64
    float* V   = U + (size_t)N * 64;            // N*64
    int* ib    = (int*)(V + (size_t)N * 64);
    int* deg   = ib;                            // N
    int* cur   = ib + N;                        // N
    int* bsum  = ib + 2 * N;                    // <=1024
    int* col   = ib + 2 * N + 1024;             // E
    float* H   = out;

    hipMemsetAsync(deg, 0, (size_t)N * sizeof(int), stream);

    k_hist<<<SCAT_BLOCKS, TPB, 0, stream>>>(ei, deg, E);
    k_red<<<NB, TPB, 0, stream>>>(deg, bsum, N);
    k_apply2<<<NB, TPB, 0, stream>>>(deg, bsum, cur, N);
    k_scatter2<<<SCAT_BLOCKS, TPB, 0, stream>>>(ei, cur, col, eas, ea, E);

    k_prep4<<<PREP_BLOCKS, TPB, 0, stream>>>(x, ew1, eb1, U, V, N);

    k_edge10<<<EDGE_BLOCKS, TPB, 0, stream>>>(
        U, V, eas, col, ew1, deg, cur, H, N);

    k_node4<<<NODE_BLOCKS, TPB, 0, stream>>>(
        x, H, deg, ew2, eb2, nw1, nb1, nw2, nb2, out, N);
  } else {
    // r12 fallback
    float* U   = (float*)d_ws;
    float* V   = U + (size_t)N * 64;
    int* ib    = (int*)(V + (size_t)N * 64);
    int* deg   = ib;
    int* cur   = ib + N;
    int* bsum  = ib + 2 * N;
    int2* ec   = (int2*)(ib + 2 * N + 1024);
    float* H   = out;

    hipMemsetAsync(deg, 0, (size_t)N * sizeof(int), stream);

    k_hist<<<SCAT_BLOCKS, TPB, 0, stream>>>(ei, deg, E);
    k_red<<<NB, TPB, 0, stream>>>(deg, bsum, N);
    k_apply2<<<NB, TPB, 0, stream>>>(deg, bsum, cur, N);
    k_scatter<<<SCAT_BLOCKS, TPB, 0, stream>>>(ei, cur, ec, E);

    k_prep4<<<PREP_BLOCKS, TPB, 0, stream>>>(x, ew1, eb1, U, V, N);

    k_edge9<<<EDGE_BLOCKS, TPB, 0, stream>>>(
        U, V, ea, ew1, deg, cur, ec, H, N);

    k_node4<<<NODE_BLOCKS, TPB, 0, stream>>>(
        x, H, deg, ew2, eb2, nw1, nb1, nw2, nb2, out, N);
  }
}

// Round 14
// 572.449 us; speedup vs baseline: 1.1290x; 1.1290x over previous
//
#include <hip/hip_runtime.h>
#include <hip/hip_bf16.h>

// GraphMatchingLayer, round 14: r12 structure + bf16-packed ea broadcast.
// r13 post-mortem: scalar-path ea (random OR sequential) is a dead end (k$
// miss-queue serialization). The real edge floor is LDS *return bandwidth*
// (8KB broadcast/edge = 64cyc/edge/CU = ~167us). Fix: halve the broadcast.
//  - k_scatter2b: ea rows -> RNE bf16, stored CSR-ordered (easb, 64B rows)
//  - k_edge11: 16-edge chunks, 4x ds_read_b128/edge (4KB broadcast/edge),
//    shift/and unpack (bf16<<16 == fp32), v_pk_fma with w2[16] pinned via
//    the r11-proven SINGLE asm statement.
// Fallback to r12 path if ws too small.

#define TPB 256
#define EDGE_BLOCKS 2048
#define SCAT_BLOCKS 2048
#define PREP_BLOCKS 1024
#define NODE_BLOCKS 1024

typedef float v2f __attribute__((ext_vector_type(2)));
typedef float v4f __attribute__((ext_vector_type(4)));
typedef unsigned int uint32;

// 32-wide dense segment (weights via wave-uniform address -> scalar loads)
#define SEG32(SRC, NCH, KB, W, COL, ACC)                                \
  for (int kc_ = 0; kc_ < (NCH); ++kc_) {                               \
    const float4 a_ = ((const float4*)(SRC))[kc_];                      \
    const float av_[4] = {a_.x, a_.y, a_.z, a_.w};                     \
    _Pragma("unroll")                                                   \
    for (int j_ = 0; j_ < 4; ++j_) {                                    \
      const float ak_ = av_[j_];                                        \
      const float* wr_ = (W) + ((KB) + kc_ * 4 + j_) * 64 + (COL);      \
      _Pragma("unroll")                                                 \
      for (int cc_ = 0; cc_ < 32; ++cc_)                                \
        ACC[cc_] = fmaf(ak_, wr_[cc_], ACC[cc_]);                       \
    }                                                                   \
  }

__device__ __forceinline__ uint32 pk_bf16(float a, float b) {
  uint32 ua = __float_as_uint(a);
  uint32 ub = __float_as_uint(b);
  ua = ua + 0x7FFFu + ((ua >> 16) & 1u);      // RNE to bf16
  ub = ub + 0x7FFFu + ((ub >> 16) & 1u);
  return (ub & 0xFFFF0000u) | (ua >> 16);
}

// ---------------- CSR build ----------------

__global__ __launch_bounds__(TPB)
void k_hist(const int* __restrict__ ei, int* __restrict__ deg, int E) {
  const int stride = gridDim.x * TPB;
  for (int e = blockIdx.x * TPB + threadIdx.x; e < E; e += stride)
    atomicAdd(&deg[ei[e]], 1);
}

__global__ __launch_bounds__(TPB)
void k_red(const int* __restrict__ deg, int* __restrict__ bsum, int N) {
  __shared__ int s[TPB];
  const int tid = threadIdx.x;
  const int g = (blockIdx.x * TPB + tid) * 4;
  int v = 0;
  #pragma unroll
  for (int j = 0; j < 4; ++j) if (g + j < N) v += deg[g + j];
  s[tid] = v;
  __syncthreads();
  for (int off = TPB / 2; off > 0; off >>= 1) {
    if (tid < off) s[tid] += s[tid + off];
    __syncthreads();
  }
  if (tid == 0) bsum[blockIdx.x] = s[0];
}

__global__ __launch_bounds__(TPB)
void k_apply2(const int* __restrict__ deg, const int* __restrict__ bsum,
              int* __restrict__ cur, int N) {
  __shared__ int s[TPB];
  __shared__ int sbase;
  const int tid = threadIdx.x;
  const int g = (blockIdx.x * TPB + tid) * 4;

  if (tid < 64) {
    int v = 0;
    for (int i = tid; i < (int)blockIdx.x; i += 64) v += bsum[i];
    #pragma unroll
    for (int off = 32; off > 0; off >>= 1) v += __shfl_down(v, off);
    if (tid == 0) sbase = v;
  }

  int d[4];
  int v = 0;
  #pragma unroll
  for (int j = 0; j < 4; ++j) { d[j] = (g + j < N) ? deg[g + j] : 0; v += d[j]; }
  s[tid] = v;
  __syncthreads();
  for (int off = 1; off < TPB; off <<= 1) {
    int t = (tid >= off) ? s[tid - off] : 0;
    __syncthreads();
    s[tid] += t;
    __syncthreads();
  }
  int base = sbase + s[tid] - v;
  #pragma unroll
  for (int j = 0; j < 4; ++j)
    if (g + j < N) { cur[g + j] = base; base += d[j]; }
}

// new path: col[p] = c; easb[p] = bf16(ea[e]) (CSR-ordered, 64B rows)
__global__ __launch_bounds__(TPB)
void k_scatter2b(const int* __restrict__ ei, int* __restrict__ cur,
                 int* __restrict__ col, uint32* __restrict__ easb,
                 const float* __restrict__ ea, int E) {
  const int stride = gridDim.x * TPB;
  for (int e = blockIdx.x * TPB + threadIdx.x; e < E; e += stride) {
    const int r = ei[e];
    const int c = ei[E + e];
    int p = atomicAdd(&cur[r], 1);
    col[p] = c;
    const float4* src = (const float4*)(ea + (size_t)e * 32);
    uint4* dst = (uint4*)(easb + (size_t)p * 16);
    #pragma unroll
    for (int j = 0; j < 4; ++j) {
      const float4 a = src[2 * j];
      const float4 b = src[2 * j + 1];
      uint4 o;
      o.x = pk_bf16(a.x, a.y);
      o.y = pk_bf16(a.z, a.w);
      o.z = pk_bf16(b.x, b.y);
      o.w = pk_bf16(b.z, b.w);
      dst[j] = o;
    }
  }
}

// fallback scatter (r12)
__global__ __launch_bounds__(TPB)
void k_scatter(const int* __restrict__ ei, int* __restrict__ cur,
               int2* __restrict__ ec, int E) {
  const int stride = gridDim.x * TPB;
  for (int e = blockIdx.x * TPB + threadIdx.x; e < E; e += stride) {
    const int r = ei[e];
    const int c = ei[E + e];
    int p = atomicAdd(&cur[r], 1);
    ec[p] = make_int2(e, c);
  }
}

// ---------------- U/V precompute ----------------

__global__ __launch_bounds__(TPB)
void k_prep4(const float* __restrict__ x,
             const float* __restrict__ ew1, const float* __restrict__ eb1,
             float* __restrict__ U, float* __restrict__ V, int N)
{
  const int lane = threadIdx.x & 63;
  const int wid  = __builtin_amdgcn_readfirstlane(threadIdx.x >> 6);
  const int nunits = 4 * ((N + 63) / 64);
  const int wstride = gridDim.x * 4;

  for (int unit = blockIdx.x * 4 + wid; unit < nunits; unit += wstride) {
    const int q = unit & 3;
    const int n = (unit >> 2) * 64 + lane;
    if (n >= N) continue;

    const int uv = q >> 1;
    const int h = (q & 1) * 32;
    const float* W = ew1 + uv * 64 * 64;

    float acc[32];
    if (uv) {
      #pragma unroll
      for (int j = 0; j < 32; ++j) acc[j] = 0.f;
    } else {
      #pragma unroll
      for (int j = 0; j < 32; ++j) acc[j] = eb1[h + j];
    }
    SEG32(x + (size_t)n * 64, 16, 0, W, h, acc)

    float* dst = (uv ? V : U) + (size_t)n * 64 + h;
    float4* d4 = (float4*)dst;
    #pragma unroll
    for (int c4 = 0; c4 < 8; ++c4)
      d4[c4] = make_float4(acc[c4*4+0], acc[c4*4+1], acc[c4*4+2], acc[c4*4+3]);
  }
}

// ---------------- edge phase: bf16 LDS broadcast, 16-edge chunks ----------------

__global__ __launch_bounds__(TPB, 4)
void k_edge11(const float* __restrict__ U, const float* __restrict__ V,
              const uint32* __restrict__ easb, const int* __restrict__ col,
              const float* __restrict__ ew1,
              const int* __restrict__ deg, const int* __restrict__ cur,
              float* __restrict__ H, int N)
{
  __shared__ uint32 sbuf[4 * 256];       // per wave: 256 uints = 1KB strip

  const int lane = threadIdx.x & 63;
  const int wid  = __builtin_amdgcn_readfirstlane(threadIdx.x >> 6);

  uint32* lw = sbuf + wid * 256;
  const int g4 = lane >> 2;              // edge slot in chunk (0..15)
  const int q4 = lane & 3;               // 16B quarter of the 64B row

  // this lane's W1c column as 16 v2f, pinned with ONE asm statement (r11 form)
  const float* wcol = ew1 + 128 * 64 + lane;
  v2f w2[16];
  #pragma unroll
  for (int i = 0; i < 16; ++i) {
    w2[i].x = wcol[(2 * i) * 64];
    w2[i].y = wcol[(2 * i + 1) * 64];
  }
  asm volatile("" : "+v"(w2[0]), "+v"(w2[1]), "+v"(w2[2]), "+v"(w2[3]),
                    "+v"(w2[4]), "+v"(w2[5]), "+v"(w2[6]), "+v"(w2[7]),
                    "+v"(w2[8]), "+v"(w2[9]), "+v"(w2[10]), "+v"(w2[11]),
                    "+v"(w2[12]), "+v"(w2[13]), "+v"(w2[14]), "+v"(w2[15]));

  const int wstride = gridDim.x * 4;

  for (int n = blockIdx.x * 4 + wid; n < N; n += wstride) {
    const int d  = __builtin_amdgcn_readfirstlane(deg[n]);
    const int s0 = __builtin_amdgcn_readfirstlane(cur[n]) - d;

    const float u = U[(size_t)n * 64 + lane];
    float acc = 0.f;

    for (int i = 0; i < d; i += 16) {
      const int rem = d - i;                  // >= 1, uniform
      const int gg = (g4 < rem) ? g4 : rem - 1;
      const int p = s0 + i + gg;

      // per-lane col (4-lane broadcast groups, sequential region)
      const int cv = col[p];
      // this lane's quarter of the bf16 row (coalesced)
      const uint4 ev = *(const uint4*)(easb + (size_t)p * 16 + q4 * 4);

      // 16 V-row loads issued up front (cols via readlane from slot lanes)
      float vv[16];
      #pragma unroll
      for (int j = 0; j < 16; ++j) {
        const int cj = __builtin_amdgcn_readlane(cv, 4 * j);
        vv[j] = V[(size_t)cj * 64 + lane];
      }

      *(uint4*)(lw + lane * 4) = ev;          // wave-private strip (in-order DS)

      #pragma unroll
      for (int j = 0; j < 16; ++j) {
        const uint32* er = lw + j * 16;       // uniform addr -> broadcast reads
        const uint4 qa = *(const uint4*)(er);
        const uint4 qb = *(const uint4*)(er + 4);
        const uint4 qc = *(const uint4*)(er + 8);
        const uint4 qd = *(const uint4*)(er + 12);
        const uint32 us[16] = {qa.x, qa.y, qa.z, qa.w, qb.x, qb.y, qb.z, qb.w,
                               qc.x, qc.y, qc.z, qc.w, qd.x, qd.y, qd.z, qd.w};
        v2f t0 = {u, 0.f}, t1 = {0.f, 0.f}, t2 = {0.f, 0.f}, t3 = {0.f, 0.f};
        #pragma unroll
        for (int m = 0; m < 16; m += 4) {
          v2f a0, a1, a2, a3;
          a0.x = __uint_as_float(us[m + 0] << 16);
          a0.y = __uint_as_float(us[m + 0] & 0xFFFF0000u);
          a1.x = __uint_as_float(us[m + 1] << 16);
          a1.y = __uint_as_float(us[m + 1] & 0xFFFF0000u);
          a2.x = __uint_as_float(us[m + 2] << 16);
          a2.y = __uint_as_float(us[m + 2] & 0xFFFF0000u);
          a3.x = __uint_as_float(us[m + 3] << 16);
          a3.y = __uint_as_float(us[m + 3] & 0xFFFF0000u);
          t0 = __builtin_elementwise_fma(a0, w2[m + 0], t0);
          t1 = __builtin_elementwise_fma(a1, w2[m + 1], t1);
          t2 = __builtin_elementwise_fma(a2, w2[m + 2], t2);
          t3 = __builtin_elementwise_fma(a3, w2[m + 3], t3);
        }
        const v2f s2 = (t0 + t1) + (t2 + t3);
        const float s = fmaxf(s2.x + s2.y + vv[j], 0.f);
        acc += (j < rem) ? s : 0.f;
      }
    }

    H[(size_t)n * 64 + lane] = acc;
  }
}

// ---------------- edge phase fallback (r12 verbatim) ----------------

__global__ __launch_bounds__(TPB, 4)
void k_edge9(const float* __restrict__ U, const float* __restrict__ V,
             const float* __restrict__ ea,
             const float* __restrict__ ew1,
             const int* __restrict__ deg, const int* __restrict__ cur,
             const int2* __restrict__ ec,
             float* __restrict__ H, int N)
{
  __shared__ float sbuf[4 * 256];

  const int lane = threadIdx.x & 63;
  const int wid  = __builtin_amdgcn_readfirstlane(threadIdx.x >> 6);

  float* lw = sbuf + wid * 256;
  const int g = lane >> 3;
  const int o = lane & 7;

  const float* wcol = ew1 + 128 * 64 + lane;
  v2f w2[16];
  #pragma unroll
  for (int i = 0; i < 16; ++i) {
    w2[i].x = wcol[(2 * i) * 64];
    w2[i].y = wcol[(2 * i + 1) * 64];
  }
  asm volatile("" : "+v"(w2[0]), "+v"(w2[1]), "+v"(w2[2]), "+v"(w2[3]),
                    "+v"(w2[4]), "+v"(w2[5]), "+v"(w2[6]), "+v"(w2[7]),
                    "+v"(w2[8]), "+v"(w2[9]), "+v"(w2[10]), "+v"(w2[11]),
                    "+v"(w2[12]), "+v"(w2[13]), "+v"(w2[14]), "+v"(w2[15]));

  const int wstride = gridDim.x * 4;

  for (int n = blockIdx.x * 4 + wid; n < N; n += wstride) {
    const int d  = __builtin_amdgcn_readfirstlane(deg[n]);
    const int s0 = __builtin_amdgcn_readfirstlane(cur[n]) - d;

    const float u = U[(size_t)n * 64 + lane];
    const int2* ecp = ec + s0;
    float acc = 0.f;

    for (int i = 0; i < d; i += 8) {
      const int rem = d - i;
      const int gg = (g < rem) ? g : rem - 1;

      const int2 ecv = ecp[i + gg];
      const float4 eav = *(const float4*)(ea + (size_t)ecv.x * 32 + o * 4);

      const int c0 = __builtin_amdgcn_readlane(ecv.y, 0);
      const int c1 = __builtin_amdgcn_readlane(ecv.y, 8);
      const int c2 = __builtin_amdgcn_readlane(ecv.y, 16);
      const int c3 = __builtin_amdgcn_readlane(ecv.y, 24);
      const int c4 = __builtin_amdgcn_readlane(ecv.y, 32);
      const int c5 = __builtin_amdgcn_readlane(ecv.y, 40);
      const int c6 = __builtin_amdgcn_readlane(ecv.y, 48);
      const int c7 = __builtin_amdgcn_readlane(ecv.y, 56);
      const float v0 = V[(size_t)c0 * 64 + lane];
      const float v1 = V[(size_t)c1 * 64 + lane];
      const float v2 = V[(size_t)c2 * 64 + lane];
      const float v3 = V[(size_t)c3 * 64 + lane];
      const float v4 = V[(size_t)c4 * 64 + lane];
      const float v5 = V[(size_t)c5 * 64 + lane];
      const float v6 = V[(size_t)c6 * 64 + lane];
      const float v7 = V[(size_t)c7 * 64 + lane];

      *(float4*)(lw + lane * 4) = eav;

      const float vs[8] = {v0, v1, v2, v3, v4, v5, v6, v7};
      #pragma unroll
      for (int j = 0; j < 8; ++j) {
        const float* er = lw + j * 32;
        v2f t0 = {u, 0.f}, t1 = {0.f, 0.f}, t2 = {0.f, 0.f}, t3 = {0.f, 0.f};
        #pragma unroll
        for (int kq = 0; kq < 8; kq += 2) {
          const v4f qa = *(const v4f*)(er + kq * 4);
          const v4f qb = *(const v4f*)(er + kq * 4 + 4);
          t0 = __builtin_elementwise_fma(qa.lo, w2[2 * kq],     t0);
          t1 = __builtin_elementwise_fma(qa.hi, w2[2 * kq + 1], t1);
          t2 = __builtin_elementwise_fma(qb.lo, w2[2 * kq + 2], t2);
          t3 = __builtin_elementwise_fma(qb.hi, w2[2 * kq + 3], t3);
        }
        const v2f s2 = (t0 + t1) + (t2 + t3);
        const float s = fmaxf(s2.x + s2.y + vs[j], 0.f);
        acc += (j < rem) ? s : 0.f;
      }
    }

    H[(size_t)n * 64 + lane] = acc;
  }
}

// ---------------- node MLP (grid-stride) ----------------

__global__ __launch_bounds__(TPB)
void k_node4(const float* __restrict__ x, const float* __restrict__ Hin,
             const int* __restrict__ deg,
             const float* __restrict__ ew2, const float* __restrict__ eb2,
             const float* __restrict__ nw1, const float* __restrict__ nb1,
             const float* __restrict__ nw2, const float* __restrict__ nb2,
             float* __restrict__ out, int N)
{
  __shared__ float sb[2][64 * 65];

  const int tid  = threadIdx.x;
  const int wv   = __builtin_amdgcn_readfirstlane(tid >> 6);
  const int lane = tid & 63;
  const int grp  = wv >> 1;
  const int h    = (wv & 1) * 32;

  for (int base = blockIdx.x * 128; base < N; base += gridDim.x * 128) {
    const int n  = base + grp * 64 + lane;
    const bool valid = (n < N);
    const int nn = valid ? n : (N - 1);

    float* srow = &sb[grp][lane * 65];

    float acc[32];
    const float dg = (float)deg[nn];
    #pragma unroll
    for (int j = 0; j < 32; ++j) acc[j] = dg * eb2[h + j];
    SEG32(Hin + (size_t)nn * 64, 16, 0, ew2, h, acc)

    #pragma unroll
    for (int j = 0; j < 32; ++j) srow[h + j] = acc[j];
    __syncthreads();

    float bcc[32];
    #pragma unroll
    for (int j = 0; j < 32; ++j) bcc[j] = nb1[h + j];
    SEG32(x + (size_t)nn * 64, 16, 0, nw1, h, bcc)
    for (int k = 0; k < 64; ++k) {
      const float ak = srow[k];
      const float* wr = nw1 + (64 + k) * 64 + h;
      #pragma unroll
      for (int cc = 0; cc < 32; ++cc) bcc[cc] = fmaf(ak, wr[cc], bcc[cc]);
    }
    __syncthreads();

    #pragma unroll
    for (int j = 0; j < 32; ++j) srow[h + j] = fmaxf(bcc[j], 0.f);
    __syncthreads();

    float occ[32];
    #pragma unroll
    for (int j = 0; j < 32; ++j) occ[j] = nb2[h + j];
    for (int k = 0; k < 64; ++k) {
      const float ak = srow[k];
      const float* wr = nw2 + k * 64 + h;
      #pragma unroll
      for (int cc = 0; cc < 32; ++cc) occ[cc] = fmaf(ak, wr[cc], occ[cc]);
    }

    if (valid) {
      float4* ov = (float4*)(out + (size_t)n * 64 + h);
      #pragma unroll
      for (int c4 = 0; c4 < 8; ++c4)
        ov[c4] = make_float4(occ[c4*4+0], occ[c4*4+1], occ[c4*4+2], occ[c4*4+3]);
    }
    __syncthreads();
  }
}

// ---------------- launch ----------------

extern "C" void kernel_launch(void* const* d_in, const int* in_sizes, int n_in,
                              void* d_out, int out_size, void* d_ws, size_t ws_size,
                              hipStream_t stream) {
  const float* x   = (const float*)d_in[0];
  const int*   ei  = (const int*)d_in[1];
  const float* ea  = (const float*)d_in[2];
  const float* ew1 = (const float*)d_in[3];
  const float* eb1 = (const float*)d_in[4];
  const float* ew2 = (const float*)d_in[5];
  const float* eb2 = (const float*)d_in[6];
  const float* nw1 = (const float*)d_in[7];
  const float* nb1 = (const float*)d_in[8];
  const float* nw2 = (const float*)d_in[9];
  const float* nb2 = (const float*)d_in[10];
  float* out = (float*)d_out;

  const int N = in_sizes[0] / 64;   // 100000
  const int E = in_sizes[1] / 2;    // 1600000

  const int NT = (N + 3) / 4;
  const int NB = (NT + TPB - 1) / TPB;

  const size_t easb_u  = (size_t)E * 16;                     // 102.4 MB (uints)
  const size_t uv_f    = 2 * (size_t)N * 64;                 // 51.2 MB
  const size_t ints    = (size_t)2 * N + 1024 + E;
  const size_t need_new = (easb_u + uv_f + ints) * 4;

  if (ws_size >= need_new) {
    uint32* easb = (uint32*)d_ws;               // E*16 uints
    float* U   = (float*)(easb + easb_u);       // N*64
    float* V   = U + (size_t)N * 64;            // N*64
    int* ib    = (int*)(V + (size_t)N * 64);
    int* deg   = ib;                            // N
    int* cur   = ib + N;                        // N
    int* bsum  = ib + 2 * N;                    // <=1024
    int* col   = ib + 2 * N + 1024;             // E
    float* H   = out;

    hipMemsetAsync(deg, 0, (size_t)N * sizeof(int), stream);

    k_hist<<<SCAT_BLOCKS, TPB, 0, stream>>>(ei, deg, E);
    k_red<<<NB, TPB, 0, stream>>>(deg, bsum, N);
    k_apply2<<<NB, TPB, 0, stream>>>(deg, bsum, cur, N);
    k_scatter2b<<<SCAT_BLOCKS, TPB, 0, stream>>>(ei, cur, col, easb, ea, E);

    k_prep4<<<PREP_BLOCKS, TPB, 0, stream>>>(x, ew1, eb1, U, V, N);

    k_edge11<<<EDGE_BLOCKS, TPB, 0, stream>>>(
        U, V, easb, col, ew1, deg, cur, H, N);

    k_node4<<<NODE_BLOCKS, TPB, 0, stream>>>(
        x, H, deg, ew2, eb2, nw1, nb1, nw2, nb2, out, N);
  } else {
    // r12 fallback
    float* U   = (float*)d_ws;
    float* V   = U + (size_t)N * 64;
    int* ib    = (int*)(V + (size_t)N * 64);
    int* deg   = ib;
    int* cur   = ib + N;
    int* bsum  = ib + 2 * N;
    int2* ec   = (int2*)(ib + 2 * N + 1024);
    float* H   = out;

    hipMemsetAsync(deg, 0, (size_t)N * sizeof(int), stream);

    k_hist<<<SCAT_BLOCKS, TPB, 0, stream>>>(ei, deg, E);
    k_red<<<NB, TPB, 0, stream>>>(deg, bsum, N);
    k_apply2<<<NB, TPB, 0, stream>>>(deg, bsum, cur, N);
    k_scatter<<<SCAT_BLOCKS, TPB, 0, stream>>>(ei, cur, ec, E);

    k_prep4<<<PREP_BLOCKS, TPB, 0, stream>>>(x, ew1, eb1, U, V, N);

    k_edge9<<<EDGE_BLOCKS, TPB, 0, stream>>>(
        U, V, ea, ew1, deg, cur, ec, H, N);

    k_node4<<<NODE_BLOCKS, TPB, 0, stream>>>(
        x, H, deg, ew2, eb2, nw1, nb1, nw2, nb2, out, N);
  }
}